// Round 5
// baseline (1504.041 us; speedup 1.0000x reference)
//
#include <hip/hip_runtime.h>
#include <hip/hip_fp16.h>

#define TPB 256
#define TPB_AGG 512
#define BUCKET_BITS 10
#define BUCKET_SZ   (1 << BUCKET_BITS)       // 1024 nodes per dst-bucket
#define SRC_BITS    19                        // packed path requires n <= 2^19
#define SRC_MASK    ((1u << SRC_BITS) - 1u)
#define NB_MAX      512                       // LDS histogram capacity
#define CHUNK       32768                     // edges per partition block
#define SCAN_CHUNK  2048

// Hardware fp32 atomic for the global fallback path.
__device__ __forceinline__ void atomAddF(float* p, float v) { unsafeAtomicAdd(p, v); }

// fp16x4 load/store helpers (hs arrays are __half, 4 or 2 elems per node)
__device__ __forceinline__ float4 ld_h4(const __half* p, int node) {
    uint2 raw = *(const uint2*)(p + (size_t)node * 4);   // single 8B load
    __half2 ab = *reinterpret_cast<__half2*>(&raw.x);
    __half2 cd = *reinterpret_cast<__half2*>(&raw.y);
    float2 f01 = __half22float2(ab);
    float2 f23 = __half22float2(cd);
    return make_float4(f01.x, f01.y, f23.x, f23.y);
}
__device__ __forceinline__ void st_h4(__half* p, int node, float4 v) {
    __half2 h01 = __float22half2_rn(make_float2(v.x, v.y));
    __half2 h23 = __float22half2_rn(make_float2(v.z, v.w));
    uint2 raw;
    raw.x = *reinterpret_cast<unsigned*>(&h01);
    raw.y = *reinterpret_cast<unsigned*>(&h23);
    *(uint2*)(p + (size_t)node * 4) = raw;
}
__device__ __forceinline__ float2 ld_h2(const __half* p, int node) {
    __half2 h = *(const __half2*)(p + (size_t)node * 2);
    return __half22float2(h);
}
__device__ __forceinline__ void st_h2(__half* p, int node, float2 v) {
    *(__half2*)(p + (size_t)node * 2) = __float22half2_rn(v);
}

// ============================ dense transform ============================

// ---- layer 1 transform: hs1 = dinv * (x @ W1)  [fp16 out] ----
__global__ __launch_bounds__(TPB) void k_xform1(const float* __restrict__ x,
                                                const float* __restrict__ W,
                                                const float* __restrict__ dinv,
                                                __half* __restrict__ hs, int n) {
    int node = blockIdx.x * (TPB / 32) + (threadIdx.x >> 5);
    int lane = threadIdx.x & 31;
    if (node >= n) return;
    int k = lane * 4;
    float4 xv = *(const float4*)(x + (size_t)node * 128 + k);
    float4 w0 = *(const float4*)(W + (size_t)(k + 0) * 4);
    float4 w1 = *(const float4*)(W + (size_t)(k + 1) * 4);
    float4 w2 = *(const float4*)(W + (size_t)(k + 2) * 4);
    float4 w3 = *(const float4*)(W + (size_t)(k + 3) * 4);
    float p0 = xv.x * w0.x + xv.y * w1.x + xv.z * w2.x + xv.w * w3.x;
    float p1 = xv.x * w0.y + xv.y * w1.y + xv.z * w2.y + xv.w * w3.y;
    float p2 = xv.x * w0.z + xv.y * w1.z + xv.z * w2.z + xv.w * w3.z;
    float p3 = xv.x * w0.w + xv.y * w1.w + xv.z * w2.w + xv.w * w3.w;
#pragma unroll
    for (int off = 16; off >= 1; off >>= 1) {
        p0 += __shfl_down(p0, off, 32);
        p1 += __shfl_down(p1, off, 32);
        p2 += __shfl_down(p2, off, 32);
        p3 += __shfl_down(p3, off, 32);
    }
    if (lane == 0) {
        float dv = dinv[node];
        st_h4(hs, node, make_float4(dv * p0, dv * p1, dv * p2, dv * p3));
    }
}

// ============================ scan (two-level) ============================

__global__ __launch_bounds__(TPB) void k_scan_block(const int* __restrict__ in,
                                                    int* __restrict__ out,
                                                    int* __restrict__ blockSums, int n) {
    __shared__ int waveTot[TPB / 64];
    int base = blockIdx.x * SCAN_CHUNK + threadIdx.x * 8;
    int v[8];
    int s = 0;
#pragma unroll
    for (int j = 0; j < 8; j++) {
        int idx = base + j;
        int xval = (idx < n) ? in[idx] : 0;
        v[j] = s;
        s += xval;
    }
    int lane = threadIdx.x & 63, wave = threadIdx.x >> 6;
    int t = s;
#pragma unroll
    for (int off = 1; off < 64; off <<= 1) {
        int u = __shfl_up(t, off, 64);
        if (lane >= off) t += u;
    }
    if (lane == 63) waveTot[wave] = t;
    __syncthreads();
    int waveOff = 0;
    for (int w = 0; w < wave; w++) waveOff += waveTot[w];
    int myStart = waveOff + (t - s);
#pragma unroll
    for (int j = 0; j < 8; j++) {
        int idx = base + j;
        if (idx < n) out[idx] = myStart + v[j];
    }
    if (threadIdx.x == TPB - 1) blockSums[blockIdx.x] = waveOff + t;
}

__global__ __launch_bounds__(TPB) void k_scan_add(int* __restrict__ out,
                                                  const int* __restrict__ blockSums, int n) {
    int i = blockIdx.x * TPB + threadIdx.x;
    if (i >= n) return;
    out[i] += blockSums[i / SCAN_CHUNK];
}

// ===================== bucket partition (no global atomics) =====================

__global__ __launch_bounds__(TPB) void k_hist(const int* __restrict__ dst, int E,
                                              int* __restrict__ hist,
                                              int NB, int nChunks) {
    __shared__ int h[NB_MAX];
    for (int j = threadIdx.x; j < NB_MAX; j += TPB) h[j] = 0;
    __syncthreads();
    int base = blockIdx.x * CHUNK;
    int end = min(base + CHUNK, E);
    int cnt4 = (end - base) >> 2;
    const int4* d4 = (const int4*)(dst + base);
    for (int i = threadIdx.x; i < cnt4; i += TPB) {
        int4 d = d4[i];
        atomicAdd(&h[d.x >> BUCKET_BITS], 1);
        atomicAdd(&h[d.y >> BUCKET_BITS], 1);
        atomicAdd(&h[d.z >> BUCKET_BITS], 1);
        atomicAdd(&h[d.w >> BUCKET_BITS], 1);
    }
    for (int i = base + (cnt4 << 2) + threadIdx.x; i < end; i += TPB)
        atomicAdd(&h[dst[i] >> BUCKET_BITS], 1);
    __syncthreads();
    for (int j = threadIdx.x; j < NB; j += TPB)
        hist[(size_t)j * nChunks + blockIdx.x] = h[j];
}

__global__ __launch_bounds__(TPB) void k_part(const int* __restrict__ src,
                                              const int* __restrict__ dst, int E,
                                              const int* __restrict__ scanned,
                                              unsigned* __restrict__ packed,
                                              int NB, int nChunks) {
    __shared__ int offs[NB_MAX];
    for (int j = threadIdx.x; j < NB; j += TPB)
        offs[j] = scanned[(size_t)j * nChunks + blockIdx.x];
    __syncthreads();
    int base = blockIdx.x * CHUNK;
    int end = min(base + CHUNK, E);
    int cnt4 = (end - base) >> 2;
    const int4* s4 = (const int4*)(src + base);
    const int4* d4 = (const int4*)(dst + base);
    for (int i = threadIdx.x; i < cnt4; i += TPB) {
        int4 s = s4[i];
        int4 d = d4[i];
        int b, p;
        b = d.x >> BUCKET_BITS; p = atomicAdd(&offs[b], 1);
        packed[p] = ((unsigned)(d.x & (BUCKET_SZ - 1)) << SRC_BITS) | (unsigned)s.x;
        b = d.y >> BUCKET_BITS; p = atomicAdd(&offs[b], 1);
        packed[p] = ((unsigned)(d.y & (BUCKET_SZ - 1)) << SRC_BITS) | (unsigned)s.y;
        b = d.z >> BUCKET_BITS; p = atomicAdd(&offs[b], 1);
        packed[p] = ((unsigned)(d.z & (BUCKET_SZ - 1)) << SRC_BITS) | (unsigned)s.z;
        b = d.w >> BUCKET_BITS; p = atomicAdd(&offs[b], 1);
        packed[p] = ((unsigned)(d.w & (BUCKET_SZ - 1)) << SRC_BITS) | (unsigned)s.w;
    }
    for (int e = base + (cnt4 << 2) + threadIdx.x; e < end; e += TPB) {
        int s = src[e], d = dst[e];
        int b = d >> BUCKET_BITS;
        int p = atomicAdd(&offs[b], 1);
        packed[p] = ((unsigned)(d & (BUCKET_SZ - 1)) << SRC_BITS) | (unsigned)s;
    }
}

// ---- per-bucket degree count -> dinv ----
__global__ __launch_bounds__(TPB_AGG) void k_deg(const unsigned* __restrict__ packed,
                                                 const int* __restrict__ scanned,
                                                 int E, int n, int NB, int nChunks,
                                                 float* __restrict__ dinv) {
    __shared__ int cnt[BUCKET_SZ];
    int bk = blockIdx.x, tid = threadIdx.x;
    int base = bk << BUCKET_BITS;
    int nNodes = min(BUCKET_SZ, n - base);
    int s0 = scanned[(size_t)bk * nChunks];
    int s1 = (bk + 1 < NB) ? scanned[(size_t)(bk + 1) * nChunks] : E;
    for (int j = tid; j < BUCKET_SZ; j += TPB_AGG) cnt[j] = 0;
    __syncthreads();
    int a0 = (s0 + 3) & ~3; if (a0 > s1) a0 = s1;
    int a1 = s1 & ~3;
    if (tid < a0 - s0) atomicAdd(&cnt[packed[s0 + tid] >> SRC_BITS], 1);
    const uint4* p4 = (const uint4*)packed;
    for (int i = (a0 >> 2) + tid; i < (a1 >> 2); i += TPB_AGG) {
        uint4 u = p4[i];
        atomicAdd(&cnt[u.x >> SRC_BITS], 1);
        atomicAdd(&cnt[u.y >> SRC_BITS], 1);
        atomicAdd(&cnt[u.z >> SRC_BITS], 1);
        atomicAdd(&cnt[u.w >> SRC_BITS], 1);
    }
    if (a1 >= a0 && tid < s1 - a1) atomicAdd(&cnt[packed[a1 + tid] >> SRC_BITS], 1);
    __syncthreads();
    for (int j = tid; j < nNodes; j += TPB_AGG)
        dinv[base + j] = rsqrtf((float)(cnt[j] + 1));
}

// ===================== LDS-scatter aggregation layers (fp16 hs) =====================

// 4-wide in, 4-wide out (W is 4x4 row-major)
__global__ __launch_bounds__(TPB_AGG) void k_agg4to4(const unsigned* __restrict__ packed,
                                                     const int* __restrict__ scanned,
                                                     int E, int n, int NB, int nChunks,
                                                     const __half* __restrict__ hs_in,
                                                     const float* __restrict__ dinv,
                                                     const float* __restrict__ W,
                                                     const float* __restrict__ b,
                                                     __half* __restrict__ hs_out) {
    __shared__ float acc[4 * BUCKET_SZ];
    int bk = blockIdx.x, tid = threadIdx.x;
    int base = bk << BUCKET_BITS;
    int nNodes = min(BUCKET_SZ, n - base);
    int s0 = scanned[(size_t)bk * nChunks];
    int s1 = (bk + 1 < NB) ? scanned[(size_t)(bk + 1) * nChunks] : E;
    for (int j = tid; j < 4 * BUCKET_SZ; j += TPB_AGG) acc[j] = 0.f;
    __syncthreads();

    auto accum = [&](unsigned u, float4 v) {
        int ld = (int)(u >> SRC_BITS);
        atomicAdd(&acc[0 * BUCKET_SZ + ld], v.x);
        atomicAdd(&acc[1 * BUCKET_SZ + ld], v.y);
        atomicAdd(&acc[2 * BUCKET_SZ + ld], v.z);
        atomicAdd(&acc[3 * BUCKET_SZ + ld], v.w);
    };
    int a0 = (s0 + 3) & ~3; if (a0 > s1) a0 = s1;
    int a1 = s1 & ~3;
    if (tid < a0 - s0) {
        unsigned u = packed[s0 + tid];
        accum(u, ld_h4(hs_in, (int)(u & SRC_MASK)));
    }
    const uint4* p4 = (const uint4*)packed;
    int i4end = (a1 >> 2);
    int i = (a0 >> 2) + tid;
    // unroll x2: 8 independent gathers in flight before the LDS atomics
    for (; i + TPB_AGG < i4end; i += 2 * TPB_AGG) {
        uint4 ua = p4[i];
        uint4 ub = p4[i + TPB_AGG];
        float4 va0 = ld_h4(hs_in, (int)(ua.x & SRC_MASK));
        float4 va1 = ld_h4(hs_in, (int)(ua.y & SRC_MASK));
        float4 va2 = ld_h4(hs_in, (int)(ua.z & SRC_MASK));
        float4 va3 = ld_h4(hs_in, (int)(ua.w & SRC_MASK));
        float4 vb0 = ld_h4(hs_in, (int)(ub.x & SRC_MASK));
        float4 vb1 = ld_h4(hs_in, (int)(ub.y & SRC_MASK));
        float4 vb2 = ld_h4(hs_in, (int)(ub.z & SRC_MASK));
        float4 vb3 = ld_h4(hs_in, (int)(ub.w & SRC_MASK));
        accum(ua.x, va0); accum(ua.y, va1); accum(ua.z, va2); accum(ua.w, va3);
        accum(ub.x, vb0); accum(ub.y, vb1); accum(ub.z, vb2); accum(ub.w, vb3);
    }
    for (; i < i4end; i += TPB_AGG) {
        uint4 u = p4[i];
        float4 v0 = ld_h4(hs_in, (int)(u.x & SRC_MASK));
        float4 v1 = ld_h4(hs_in, (int)(u.y & SRC_MASK));
        float4 v2 = ld_h4(hs_in, (int)(u.z & SRC_MASK));
        float4 v3 = ld_h4(hs_in, (int)(u.w & SRC_MASK));
        accum(u.x, v0); accum(u.y, v1); accum(u.z, v2); accum(u.w, v3);
    }
    if (a1 >= a0 && tid < s1 - a1) {
        unsigned u = packed[a1 + tid];
        accum(u, ld_h4(hs_in, (int)(u & SRC_MASK)));
    }
    __syncthreads();

    float W00 = W[0],  W01 = W[1],  W02 = W[2],  W03 = W[3];
    float W10 = W[4],  W11 = W[5],  W12 = W[6],  W13 = W[7];
    float W20 = W[8],  W21 = W[9],  W22 = W[10], W23 = W[11];
    float W30 = W[12], W31 = W[13], W32 = W[14], W33 = W[15];
    float b0 = b[0], b1 = b[1], b2 = b[2], b3 = b[3];
    for (int j = tid; j < nNodes; j += TPB_AGG) {
        int node = base + j;
        float4 self = ld_h4(hs_in, node);
        float dv = dinv[node];
        float t0 = acc[0 * BUCKET_SZ + j] + self.x;
        float t1 = acc[1 * BUCKET_SZ + j] + self.y;
        float t2 = acc[2 * BUCKET_SZ + j] + self.z;
        float t3 = acc[3 * BUCKET_SZ + j] + self.w;
        float h0 = fmaxf(fmaf(dv, t0, b0), 0.f);
        float h1 = fmaxf(fmaf(dv, t1, b1), 0.f);
        float h2 = fmaxf(fmaf(dv, t2, b2), 0.f);
        float h3 = fmaxf(fmaf(dv, t3, b3), 0.f);
        float4 r;
        r.x = dv * (h0 * W00 + h1 * W10 + h2 * W20 + h3 * W30);
        r.y = dv * (h0 * W01 + h1 * W11 + h2 * W21 + h3 * W31);
        r.z = dv * (h0 * W02 + h1 * W12 + h2 * W22 + h3 * W32);
        r.w = dv * (h0 * W03 + h1 * W13 + h2 * W23 + h3 * W33);
        st_h4(hs_out, node, r);
    }
}

// 4-wide in, 2-wide out (W is 4x2 row-major)
__global__ __launch_bounds__(TPB_AGG) void k_agg4to2(const unsigned* __restrict__ packed,
                                                     const int* __restrict__ scanned,
                                                     int E, int n, int NB, int nChunks,
                                                     const __half* __restrict__ hs_in,
                                                     const float* __restrict__ dinv,
                                                     const float* __restrict__ W,
                                                     const float* __restrict__ b,
                                                     __half* __restrict__ hs_out) {
    __shared__ float acc[4 * BUCKET_SZ];
    int bk = blockIdx.x, tid = threadIdx.x;
    int base = bk << BUCKET_BITS;
    int nNodes = min(BUCKET_SZ, n - base);
    int s0 = scanned[(size_t)bk * nChunks];
    int s1 = (bk + 1 < NB) ? scanned[(size_t)(bk + 1) * nChunks] : E;
    for (int j = tid; j < 4 * BUCKET_SZ; j += TPB_AGG) acc[j] = 0.f;
    __syncthreads();

    auto accum = [&](unsigned u, float4 v) {
        int ld = (int)(u >> SRC_BITS);
        atomicAdd(&acc[0 * BUCKET_SZ + ld], v.x);
        atomicAdd(&acc[1 * BUCKET_SZ + ld], v.y);
        atomicAdd(&acc[2 * BUCKET_SZ + ld], v.z);
        atomicAdd(&acc[3 * BUCKET_SZ + ld], v.w);
    };
    int a0 = (s0 + 3) & ~3; if (a0 > s1) a0 = s1;
    int a1 = s1 & ~3;
    if (tid < a0 - s0) {
        unsigned u = packed[s0 + tid];
        accum(u, ld_h4(hs_in, (int)(u & SRC_MASK)));
    }
    const uint4* p4 = (const uint4*)packed;
    int i4end = (a1 >> 2);
    int i = (a0 >> 2) + tid;
    for (; i + TPB_AGG < i4end; i += 2 * TPB_AGG) {
        uint4 ua = p4[i];
        uint4 ub = p4[i + TPB_AGG];
        float4 va0 = ld_h4(hs_in, (int)(ua.x & SRC_MASK));
        float4 va1 = ld_h4(hs_in, (int)(ua.y & SRC_MASK));
        float4 va2 = ld_h4(hs_in, (int)(ua.z & SRC_MASK));
        float4 va3 = ld_h4(hs_in, (int)(ua.w & SRC_MASK));
        float4 vb0 = ld_h4(hs_in, (int)(ub.x & SRC_MASK));
        float4 vb1 = ld_h4(hs_in, (int)(ub.y & SRC_MASK));
        float4 vb2 = ld_h4(hs_in, (int)(ub.z & SRC_MASK));
        float4 vb3 = ld_h4(hs_in, (int)(ub.w & SRC_MASK));
        accum(ua.x, va0); accum(ua.y, va1); accum(ua.z, va2); accum(ua.w, va3);
        accum(ub.x, vb0); accum(ub.y, vb1); accum(ub.z, vb2); accum(ub.w, vb3);
    }
    for (; i < i4end; i += TPB_AGG) {
        uint4 u = p4[i];
        float4 v0 = ld_h4(hs_in, (int)(u.x & SRC_MASK));
        float4 v1 = ld_h4(hs_in, (int)(u.y & SRC_MASK));
        float4 v2 = ld_h4(hs_in, (int)(u.z & SRC_MASK));
        float4 v3 = ld_h4(hs_in, (int)(u.w & SRC_MASK));
        accum(u.x, v0); accum(u.y, v1); accum(u.z, v2); accum(u.w, v3);
    }
    if (a1 >= a0 && tid < s1 - a1) {
        unsigned u = packed[a1 + tid];
        accum(u, ld_h4(hs_in, (int)(u & SRC_MASK)));
    }
    __syncthreads();

    float W00 = W[0], W01 = W[1];
    float W10 = W[2], W11 = W[3];
    float W20 = W[4], W21 = W[5];
    float W30 = W[6], W31 = W[7];
    float b0 = b[0], b1 = b[1], b2 = b[2], b3 = b[3];
    for (int j = tid; j < nNodes; j += TPB_AGG) {
        int node = base + j;
        float4 self = ld_h4(hs_in, node);
        float dv = dinv[node];
        float t0 = acc[0 * BUCKET_SZ + j] + self.x;
        float t1 = acc[1 * BUCKET_SZ + j] + self.y;
        float t2 = acc[2 * BUCKET_SZ + j] + self.z;
        float t3 = acc[3 * BUCKET_SZ + j] + self.w;
        float h0 = fmaxf(fmaf(dv, t0, b0), 0.f);
        float h1 = fmaxf(fmaf(dv, t1, b1), 0.f);
        float h2 = fmaxf(fmaf(dv, t2, b2), 0.f);
        float h3 = fmaxf(fmaf(dv, t3, b3), 0.f);
        float2 r;
        r.x = dv * (h0 * W00 + h1 * W10 + h2 * W20 + h3 * W30);
        r.y = dv * (h0 * W01 + h1 * W11 + h2 * W21 + h3 * W31);
        st_h2(hs_out, node, r);
    }
}

// 2-wide in, out = dv*agg + b3 (fp32 out, no relu)
__global__ __launch_bounds__(TPB_AGG) void k_agg2out(const unsigned* __restrict__ packed,
                                                     const int* __restrict__ scanned,
                                                     int E, int n, int NB, int nChunks,
                                                     const __half* __restrict__ hs_in,
                                                     const float* __restrict__ dinv,
                                                     const float* __restrict__ b,
                                                     float* __restrict__ out) {
    __shared__ float acc[2 * BUCKET_SZ];
    int bk = blockIdx.x, tid = threadIdx.x;
    int base = bk << BUCKET_BITS;
    int nNodes = min(BUCKET_SZ, n - base);
    int s0 = scanned[(size_t)bk * nChunks];
    int s1 = (bk + 1 < NB) ? scanned[(size_t)(bk + 1) * nChunks] : E;
    for (int j = tid; j < 2 * BUCKET_SZ; j += TPB_AGG) acc[j] = 0.f;
    __syncthreads();

    auto accum = [&](unsigned u, float2 v) {
        int ld = (int)(u >> SRC_BITS);
        atomicAdd(&acc[0 * BUCKET_SZ + ld], v.x);
        atomicAdd(&acc[1 * BUCKET_SZ + ld], v.y);
    };
    int a0 = (s0 + 3) & ~3; if (a0 > s1) a0 = s1;
    int a1 = s1 & ~3;
    if (tid < a0 - s0) {
        unsigned u = packed[s0 + tid];
        accum(u, ld_h2(hs_in, (int)(u & SRC_MASK)));
    }
    const uint4* p4 = (const uint4*)packed;
    int i4end = (a1 >> 2);
    int i = (a0 >> 2) + tid;
    for (; i + TPB_AGG < i4end; i += 2 * TPB_AGG) {
        uint4 ua = p4[i];
        uint4 ub = p4[i + TPB_AGG];
        float2 va0 = ld_h2(hs_in, (int)(ua.x & SRC_MASK));
        float2 va1 = ld_h2(hs_in, (int)(ua.y & SRC_MASK));
        float2 va2 = ld_h2(hs_in, (int)(ua.z & SRC_MASK));
        float2 va3 = ld_h2(hs_in, (int)(ua.w & SRC_MASK));
        float2 vb0 = ld_h2(hs_in, (int)(ub.x & SRC_MASK));
        float2 vb1 = ld_h2(hs_in, (int)(ub.y & SRC_MASK));
        float2 vb2 = ld_h2(hs_in, (int)(ub.z & SRC_MASK));
        float2 vb3 = ld_h2(hs_in, (int)(ub.w & SRC_MASK));
        accum(ua.x, va0); accum(ua.y, va1); accum(ua.z, va2); accum(ua.w, va3);
        accum(ub.x, vb0); accum(ub.y, vb1); accum(ub.z, vb2); accum(ub.w, vb3);
    }
    for (; i < i4end; i += TPB_AGG) {
        uint4 u = p4[i];
        float2 v0 = ld_h2(hs_in, (int)(u.x & SRC_MASK));
        float2 v1 = ld_h2(hs_in, (int)(u.y & SRC_MASK));
        float2 v2 = ld_h2(hs_in, (int)(u.z & SRC_MASK));
        float2 v3 = ld_h2(hs_in, (int)(u.w & SRC_MASK));
        accum(u.x, v0); accum(u.y, v1); accum(u.z, v2); accum(u.w, v3);
    }
    if (a1 >= a0 && tid < s1 - a1) {
        unsigned u = packed[a1 + tid];
        accum(u, ld_h2(hs_in, (int)(u & SRC_MASK)));
    }
    __syncthreads();

    float b0 = b[0], b1 = b[1];
    for (int j = tid; j < nNodes; j += TPB_AGG) {
        int node = base + j;
        float2 self = ld_h2(hs_in, node);
        float dv = dinv[node];
        float t0 = acc[0 * BUCKET_SZ + j] + self.x;
        float t1 = acc[1 * BUCKET_SZ + j] + self.y;
        float2 o;
        o.x = fmaf(dv, t0, b0);
        o.y = fmaf(dv, t1, b1);
        *(float2*)(out + (size_t)node * 2) = o;
    }
}

// ==================== fallback (round-1 global-atomic path, fp32, verified) ====================

__global__ __launch_bounds__(TPB) void k_degree(const int* __restrict__ dst,
                                                int* __restrict__ deg, int E) {
    int e4 = E >> 2;
    int i = blockIdx.x * TPB + threadIdx.x;
    if (i < e4) {
        int4 d = ((const int4*)dst)[i];
        atomicAdd(&deg[d.x], 1);
        atomicAdd(&deg[d.y], 1);
        atomicAdd(&deg[d.z], 1);
        atomicAdd(&deg[d.w], 1);
    }
    if (i < (E & 3)) atomicAdd(&deg[dst[(e4 << 2) + i]], 1);
}

__global__ __launch_bounds__(TPB) void k_dinv(const int* __restrict__ deg,
                                              float* __restrict__ dinv, int n) {
    int i = blockIdx.x * TPB + threadIdx.x;
    if (i >= n) return;
    dinv[i] = rsqrtf((float)(deg[i] + 1));
}

__global__ __launch_bounds__(TPB) void k_xform1_acc(const float* __restrict__ x,
                                                    const float* __restrict__ W,
                                                    const float* __restrict__ dinv,
                                                    float* __restrict__ hs,
                                                    float* __restrict__ acc, int n) {
    int node = blockIdx.x * (TPB / 32) + (threadIdx.x >> 5);
    int lane = threadIdx.x & 31;
    if (node >= n) return;
    int k = lane * 4;
    float4 xv = *(const float4*)(x + (size_t)node * 128 + k);
    float4 w0 = *(const float4*)(W + (size_t)(k + 0) * 4);
    float4 w1 = *(const float4*)(W + (size_t)(k + 1) * 4);
    float4 w2 = *(const float4*)(W + (size_t)(k + 2) * 4);
    float4 w3 = *(const float4*)(W + (size_t)(k + 3) * 4);
    float p0 = xv.x * w0.x + xv.y * w1.x + xv.z * w2.x + xv.w * w3.x;
    float p1 = xv.x * w0.y + xv.y * w1.y + xv.z * w2.y + xv.w * w3.y;
    float p2 = xv.x * w0.z + xv.y * w1.z + xv.z * w2.z + xv.w * w3.z;
    float p3 = xv.x * w0.w + xv.y * w1.w + xv.z * w2.w + xv.w * w3.w;
#pragma unroll
    for (int off = 16; off >= 1; off >>= 1) {
        p0 += __shfl_down(p0, off, 32);
        p1 += __shfl_down(p1, off, 32);
        p2 += __shfl_down(p2, off, 32);
        p3 += __shfl_down(p3, off, 32);
    }
    if (lane == 0) {
        float dv = dinv[node];
        float4 r = make_float4(dv * p0, dv * p1, dv * p2, dv * p3);
        *(float4*)(hs + (size_t)node * 4)  = r;
        *(float4*)(acc + (size_t)node * 4) = r;
    }
}

__global__ __launch_bounds__(TPB) void k_scatter4(const int* __restrict__ src,
                                                  const int* __restrict__ dst,
                                                  const float* __restrict__ hs,
                                                  float* __restrict__ acc, int E) {
    int e4 = E >> 2;
    int i = blockIdx.x * TPB + threadIdx.x;
    if (i < e4) {
        int4 s = ((const int4*)src)[i];
        int4 d = ((const int4*)dst)[i];
        float4 v0 = *(const float4*)(hs + (size_t)s.x * 4);
        float4 v1 = *(const float4*)(hs + (size_t)s.y * 4);
        float4 v2 = *(const float4*)(hs + (size_t)s.z * 4);
        float4 v3 = *(const float4*)(hs + (size_t)s.w * 4);
        float* a;
        a = acc + (size_t)d.x * 4;
        atomAddF(a + 0, v0.x); atomAddF(a + 1, v0.y); atomAddF(a + 2, v0.z); atomAddF(a + 3, v0.w);
        a = acc + (size_t)d.y * 4;
        atomAddF(a + 0, v1.x); atomAddF(a + 1, v1.y); atomAddF(a + 2, v1.z); atomAddF(a + 3, v1.w);
        a = acc + (size_t)d.z * 4;
        atomAddF(a + 0, v2.x); atomAddF(a + 1, v2.y); atomAddF(a + 2, v2.z); atomAddF(a + 3, v2.w);
        a = acc + (size_t)d.w * 4;
        atomAddF(a + 0, v3.x); atomAddF(a + 1, v3.y); atomAddF(a + 2, v3.z); atomAddF(a + 3, v3.w);
    }
    if (i < (E & 3)) {
        int e = (e4 << 2) + i;
        int s = src[e], d = dst[e];
        float4 v = *(const float4*)(hs + (size_t)s * 4);
        float* a = acc + (size_t)d * 4;
        atomAddF(a + 0, v.x); atomAddF(a + 1, v.y); atomAddF(a + 2, v.z); atomAddF(a + 3, v.w);
    }
}

__global__ __launch_bounds__(TPB) void k_scatter2(const int* __restrict__ src,
                                                  const int* __restrict__ dst,
                                                  const float* __restrict__ hs,
                                                  float* __restrict__ acc, int E) {
    int e4 = E >> 2;
    int i = blockIdx.x * TPB + threadIdx.x;
    if (i < e4) {
        int4 s = ((const int4*)src)[i];
        int4 d = ((const int4*)dst)[i];
        float2 v0 = *(const float2*)(hs + (size_t)s.x * 2);
        float2 v1 = *(const float2*)(hs + (size_t)s.y * 2);
        float2 v2 = *(const float2*)(hs + (size_t)s.z * 2);
        float2 v3 = *(const float2*)(hs + (size_t)s.w * 2);
        float* a;
        a = acc + (size_t)d.x * 2; atomAddF(a + 0, v0.x); atomAddF(a + 1, v0.y);
        a = acc + (size_t)d.y * 2; atomAddF(a + 0, v1.x); atomAddF(a + 1, v1.y);
        a = acc + (size_t)d.z * 2; atomAddF(a + 0, v2.x); atomAddF(a + 1, v2.y);
        a = acc + (size_t)d.w * 2; atomAddF(a + 0, v3.x); atomAddF(a + 1, v3.y);
    }
    if (i < (E & 3)) {
        int e = (e4 << 2) + i;
        int s = src[e], d = dst[e];
        float2 v = *(const float2*)(hs + (size_t)s * 2);
        float* a = acc + (size_t)d * 2;
        atomAddF(a + 0, v.x); atomAddF(a + 1, v.y);
    }
}

__global__ __launch_bounds__(TPB) void k_xform2(const float* __restrict__ acc_in,
                                                const float* __restrict__ dinv,
                                                const float* __restrict__ W,
                                                const float* __restrict__ b,
                                                float* __restrict__ hs,
                                                float* __restrict__ acc, int n) {
    int i = blockIdx.x * TPB + threadIdx.x;
    if (i >= n) return;
    float dv = dinv[i];
    float4 a = *(const float4*)(acc_in + (size_t)i * 4);
    float h0 = fmaxf(fmaf(dv, a.x, b[0]), 0.f);
    float h1 = fmaxf(fmaf(dv, a.y, b[1]), 0.f);
    float h2 = fmaxf(fmaf(dv, a.z, b[2]), 0.f);
    float h3 = fmaxf(fmaf(dv, a.w, b[3]), 0.f);
    float4 r;
    r.x = dv * (h0 * W[0] + h1 * W[4] + h2 * W[8]  + h3 * W[12]);
    r.y = dv * (h0 * W[1] + h1 * W[5] + h2 * W[9]  + h3 * W[13]);
    r.z = dv * (h0 * W[2] + h1 * W[6] + h2 * W[10] + h3 * W[14]);
    r.w = dv * (h0 * W[3] + h1 * W[7] + h2 * W[11] + h3 * W[15]);
    *(float4*)(hs + (size_t)i * 4)  = r;
    *(float4*)(acc + (size_t)i * 4) = r;
}

__global__ __launch_bounds__(TPB) void k_xform3(const float* __restrict__ acc_in,
                                                const float* __restrict__ dinv,
                                                const float* __restrict__ W,
                                                const float* __restrict__ b,
                                                float* __restrict__ hs,
                                                float* __restrict__ acc, int n) {
    int i = blockIdx.x * TPB + threadIdx.x;
    if (i >= n) return;
    float dv = dinv[i];
    float4 a = *(const float4*)(acc_in + (size_t)i * 4);
    float h0 = fmaxf(fmaf(dv, a.x, b[0]), 0.f);
    float h1 = fmaxf(fmaf(dv, a.y, b[1]), 0.f);
    float h2 = fmaxf(fmaf(dv, a.z, b[2]), 0.f);
    float h3 = fmaxf(fmaf(dv, a.w, b[3]), 0.f);
    float2 r;
    r.x = dv * (h0 * W[0] + h1 * W[2] + h2 * W[4] + h3 * W[6]);
    r.y = dv * (h0 * W[1] + h1 * W[3] + h2 * W[5] + h3 * W[7]);
    *(float2*)(hs + (size_t)i * 2)  = r;
    *(float2*)(acc + (size_t)i * 2) = r;
}

__global__ __launch_bounds__(TPB) void k_final(const float* __restrict__ acc_in,
                                               const float* __restrict__ dinv,
                                               const float* __restrict__ b,
                                               float* __restrict__ out, int n) {
    int i = blockIdx.x * TPB + threadIdx.x;
    if (i >= n) return;
    float dv = dinv[i];
    float2 a = *(const float2*)(acc_in + (size_t)i * 2);
    float2 o;
    o.x = fmaf(dv, a.x, b[0]);
    o.y = fmaf(dv, a.y, b[1]);
    *(float2*)(out + (size_t)i * 2) = o;
}

// ============================ launch ============================

extern "C" void kernel_launch(void* const* d_in, const int* in_sizes, int n_in,
                              void* d_out, int out_size, void* d_ws, size_t ws_size,
                              hipStream_t stream) {
    const float* x  = (const float*)d_in[0];
    const int*   ei = (const int*)d_in[1];
    const float* W1 = (const float*)d_in[2];
    const float* b1 = (const float*)d_in[3];
    const float* W2 = (const float*)d_in[4];
    const float* b2 = (const float*)d_in[5];
    const float* W3 = (const float*)d_in[6];
    const float* b3 = (const float*)d_in[7];
    float* out = (float*)d_out;

    const int n = in_sizes[0] / 128;   // 500000
    const int E = in_sizes[1] / 2;     // 16000000
    const int* src = ei;
    const int* dst = ei + E;
    (void)n_in; (void)out_size;

    char* ws = (char*)d_ws;
    size_t off = 0;
    auto alloc = [&](size_t bytes) -> char* {
        char* p = ws + off;
        off += (bytes + 255) & ~(size_t)255;
        return p;
    };

    const int NB = (n + BUCKET_SZ - 1) >> BUCKET_BITS;            // 489
    const int nChunks = (E + CHUNK - 1) / CHUNK;                  // 489
    const size_t histN = (size_t)NB * nChunks;
    const int nScanBlocksH = (int)((histN + SCAN_CHUNK - 1) / SCAN_CHUNK);

    int gridN  = (n + TPB - 1) / TPB;
    int gridX1 = (n + (TPB / 32) - 1) / (TPB / 32);

    // packed-path workspace requirement
    size_t need = 0;
    {
        size_t t = 0;
        auto acct = [&](size_t bytes) { t += (bytes + 255) & ~(size_t)255; };
        acct((size_t)n * 4);            // dinv
        acct((size_t)n * 8);            // hs1 (fp16 x4)
        acct((size_t)n * 8);            // hs2 (fp16 x4)
        acct((size_t)n * 4);            // hs3 (fp16 x2)
        acct((size_t)E * 4);            // packed
        acct(histN * 4);                // hist
        acct((size_t)nScanBlocksH * 4); // bsums
        acct(256);                      // dummy
        need = t;
    }

    bool packedOK = (n <= (1 << SRC_BITS)) && (NB <= NB_MAX) &&
                    (nScanBlocksH <= SCAN_CHUNK) && (ws_size >= need);

    if (packedOK) {
        float*    dinv   = (float*)alloc((size_t)n * 4);
        __half*   hs1    = (__half*)alloc((size_t)n * 8);
        __half*   hs2    = (__half*)alloc((size_t)n * 8);
        __half*   hs3    = (__half*)alloc((size_t)n * 4);
        unsigned* packed = (unsigned*)alloc((size_t)E * 4);
        int*      hist   = (int*)  alloc(histN * 4);
        int*      bsums  = (int*)  alloc((size_t)nScanBlocksH * 4);
        int*      dummy  = (int*)  alloc(256);

        // bucket-sort edges by dst (no global atomics anywhere)
        k_hist<<<nChunks, TPB, 0, stream>>>(dst, E, hist, NB, nChunks);
        k_scan_block<<<nScanBlocksH, TPB, 0, stream>>>(hist, hist, bsums, (int)histN);
        k_scan_block<<<1, TPB, 0, stream>>>(bsums, bsums, dummy, nScanBlocksH);
        k_scan_add<<<(int)((histN + TPB - 1) / TPB), TPB, 0, stream>>>(hist, bsums, (int)histN);
        k_part<<<nChunks, TPB, 0, stream>>>(src, dst, E, hist, packed, NB, nChunks);
        k_deg<<<NB, TPB_AGG, 0, stream>>>(packed, hist, E, n, NB, nChunks, dinv);

        // layers (LDS-scatter aggregation, fp16 inter-layer storage)
        k_xform1<<<gridX1, TPB, 0, stream>>>(x, W1, dinv, hs1, n);
        k_agg4to4<<<NB, TPB_AGG, 0, stream>>>(packed, hist, E, n, NB, nChunks, hs1, dinv, W2, b1, hs2);
        k_agg4to2<<<NB, TPB_AGG, 0, stream>>>(packed, hist, E, n, NB, nChunks, hs2, dinv, W3, b2, hs3);
        k_agg2out<<<NB, TPB_AGG, 0, stream>>>(packed, hist, E, n, NB, nChunks, hs3, dinv, b3, out);
    } else {
        // fallback: round-1 global-atomic scatter path (fp32, verified)
        int e4 = E >> 2;
        int gridE = (e4 > 0 ? (e4 + TPB - 1) / TPB : 1);

        int*   deg  = (int*)  alloc((size_t)n * 4);
        float* dinv = (float*)alloc((size_t)n * 4);
        float* hs1  = (float*)alloc((size_t)n * 16);
        float* acc1 = (float*)alloc((size_t)n * 16);
        float* hs2  = (float*)alloc((size_t)n * 16);
        float* acc2 = (float*)alloc((size_t)n * 16);
        float* hs3  = (float*)alloc((size_t)n * 8);
        float* acc3 = (float*)alloc((size_t)n * 8);

        hipMemsetAsync(deg, 0, (size_t)n * 4, stream);

        k_degree<<<gridE, TPB, 0, stream>>>(dst, deg, E);
        k_dinv<<<gridN, TPB, 0, stream>>>(deg, dinv, n);

        k_xform1_acc<<<gridX1, TPB, 0, stream>>>(x, W1, dinv, hs1, acc1, n);
        k_scatter4<<<gridE, TPB, 0, stream>>>(src, dst, hs1, acc1, E);
        k_xform2<<<gridN, TPB, 0, stream>>>(acc1, dinv, W2, b1, hs2, acc2, n);
        k_scatter4<<<gridE, TPB, 0, stream>>>(src, dst, hs2, acc2, E);
        k_xform3<<<gridN, TPB, 0, stream>>>(acc2, dinv, W3, b2, hs3, acc3, n);
        k_scatter2<<<gridE, TPB, 0, stream>>>(src, dst, hs3, acc3, E);
        k_final<<<gridN, TPB, 0, stream>>>(acc3, dinv, b3, out, n);
    }
}

// Round 6
// 1102.188 us; speedup vs baseline: 1.3646x; 1.3646x over previous
//
#include <hip/hip_runtime.h>
#include <hip/hip_fp16.h>

#define TPB 256
#define TPB_CSR 512
#define BUCKET_BITS 10
#define BUCKET_SZ   (1 << BUCKET_BITS)       // 1024 nodes per dst-bucket
#define SRC_BITS    19                        // packed path requires n <= 2^19
#define SRC_MASK    ((1u << SRC_BITS) - 1u)
#define NB_MAX      512                       // LDS histogram capacity
#define CHUNK       32768                     // edges per partition block
#define SCAN_CHUNK  2048

// Hardware fp32 atomic for the global fallback path.
__device__ __forceinline__ void atomAddF(float* p, float v) { unsafeAtomicAdd(p, v); }

// fp16 helpers (hs arrays are __half, 4 or 2 elems per node)
__device__ __forceinline__ float4 ld_h4(const __half* p, int node) {
    uint2 raw = *(const uint2*)(p + (size_t)node * 4);   // single 8B load
    __half2 ab = *reinterpret_cast<__half2*>(&raw.x);
    __half2 cd = *reinterpret_cast<__half2*>(&raw.y);
    float2 f01 = __half22float2(ab);
    float2 f23 = __half22float2(cd);
    return make_float4(f01.x, f01.y, f23.x, f23.y);
}
__device__ __forceinline__ void st_h4(__half* p, int node, float4 v) {
    __half2 h01 = __float22half2_rn(make_float2(v.x, v.y));
    __half2 h23 = __float22half2_rn(make_float2(v.z, v.w));
    uint2 raw;
    raw.x = *reinterpret_cast<unsigned*>(&h01);
    raw.y = *reinterpret_cast<unsigned*>(&h23);
    *(uint2*)(p + (size_t)node * 4) = raw;
}
__device__ __forceinline__ float2 ld_h2(const __half* p, int node) {
    __half2 h = *(const __half2*)(p + (size_t)node * 2);
    return __half22float2(h);
}
__device__ __forceinline__ void st_h2(__half* p, int node, float2 v) {
    *(__half2*)(p + (size_t)node * 2) = __float22half2_rn(v);
}

// ============================ dense transform ============================

// ---- layer 1 transform: hs1 = dinv * (x @ W1)  [fp16 out] ----
__global__ __launch_bounds__(TPB) void k_xform1(const float* __restrict__ x,
                                                const float* __restrict__ W,
                                                const float* __restrict__ dinv,
                                                __half* __restrict__ hs, int n) {
    int node = blockIdx.x * (TPB / 32) + (threadIdx.x >> 5);
    int lane = threadIdx.x & 31;
    if (node >= n) return;
    int k = lane * 4;
    float4 xv = *(const float4*)(x + (size_t)node * 128 + k);
    float4 w0 = *(const float4*)(W + (size_t)(k + 0) * 4);
    float4 w1 = *(const float4*)(W + (size_t)(k + 1) * 4);
    float4 w2 = *(const float4*)(W + (size_t)(k + 2) * 4);
    float4 w3 = *(const float4*)(W + (size_t)(k + 3) * 4);
    float p0 = xv.x * w0.x + xv.y * w1.x + xv.z * w2.x + xv.w * w3.x;
    float p1 = xv.x * w0.y + xv.y * w1.y + xv.z * w2.y + xv.w * w3.y;
    float p2 = xv.x * w0.z + xv.y * w1.z + xv.z * w2.z + xv.w * w3.z;
    float p3 = xv.x * w0.w + xv.y * w1.w + xv.z * w2.w + xv.w * w3.w;
#pragma unroll
    for (int off = 16; off >= 1; off >>= 1) {
        p0 += __shfl_down(p0, off, 32);
        p1 += __shfl_down(p1, off, 32);
        p2 += __shfl_down(p2, off, 32);
        p3 += __shfl_down(p3, off, 32);
    }
    if (lane == 0) {
        float dv = dinv[node];
        st_h4(hs, node, make_float4(dv * p0, dv * p1, dv * p2, dv * p3));
    }
}

// ============================ scan (two-level) ============================

__global__ __launch_bounds__(TPB) void k_scan_block(const int* __restrict__ in,
                                                    int* __restrict__ out,
                                                    int* __restrict__ blockSums, int n) {
    __shared__ int waveTot[TPB / 64];
    int base = blockIdx.x * SCAN_CHUNK + threadIdx.x * 8;
    int v[8];
    int s = 0;
#pragma unroll
    for (int j = 0; j < 8; j++) {
        int idx = base + j;
        int xval = (idx < n) ? in[idx] : 0;
        v[j] = s;
        s += xval;
    }
    int lane = threadIdx.x & 63, wave = threadIdx.x >> 6;
    int t = s;
#pragma unroll
    for (int off = 1; off < 64; off <<= 1) {
        int u = __shfl_up(t, off, 64);
        if (lane >= off) t += u;
    }
    if (lane == 63) waveTot[wave] = t;
    __syncthreads();
    int waveOff = 0;
    for (int w = 0; w < wave; w++) waveOff += waveTot[w];
    int myStart = waveOff + (t - s);
#pragma unroll
    for (int j = 0; j < 8; j++) {
        int idx = base + j;
        if (idx < n) out[idx] = myStart + v[j];
    }
    if (threadIdx.x == TPB - 1) blockSums[blockIdx.x] = waveOff + t;
}

__global__ __launch_bounds__(TPB) void k_scan_add(int* __restrict__ out,
                                                  const int* __restrict__ blockSums, int n) {
    int i = blockIdx.x * TPB + threadIdx.x;
    if (i >= n) return;
    out[i] += blockSums[i / SCAN_CHUNK];
}

// ===================== bucket partition (no global atomics) =====================

__global__ __launch_bounds__(TPB) void k_hist(const int* __restrict__ dst, int E,
                                              int* __restrict__ hist,
                                              int NB, int nChunks) {
    __shared__ int h[NB_MAX];
    for (int j = threadIdx.x; j < NB_MAX; j += TPB) h[j] = 0;
    __syncthreads();
    int base = blockIdx.x * CHUNK;
    int end = min(base + CHUNK, E);
    int cnt4 = (end - base) >> 2;
    const int4* d4 = (const int4*)(dst + base);
    for (int i = threadIdx.x; i < cnt4; i += TPB) {
        int4 d = d4[i];
        atomicAdd(&h[d.x >> BUCKET_BITS], 1);
        atomicAdd(&h[d.y >> BUCKET_BITS], 1);
        atomicAdd(&h[d.z >> BUCKET_BITS], 1);
        atomicAdd(&h[d.w >> BUCKET_BITS], 1);
    }
    for (int i = base + (cnt4 << 2) + threadIdx.x; i < end; i += TPB)
        atomicAdd(&h[dst[i] >> BUCKET_BITS], 1);
    __syncthreads();
    for (int j = threadIdx.x; j < NB; j += TPB)
        hist[(size_t)j * nChunks + blockIdx.x] = h[j];
}

__global__ __launch_bounds__(TPB) void k_part(const int* __restrict__ src,
                                              const int* __restrict__ dst, int E,
                                              const int* __restrict__ scanned,
                                              unsigned* __restrict__ packed,
                                              int NB, int nChunks) {
    __shared__ int offs[NB_MAX];
    for (int j = threadIdx.x; j < NB; j += TPB)
        offs[j] = scanned[(size_t)j * nChunks + blockIdx.x];
    __syncthreads();
    int base = blockIdx.x * CHUNK;
    int end = min(base + CHUNK, E);
    int cnt4 = (end - base) >> 2;
    const int4* s4 = (const int4*)(src + base);
    const int4* d4 = (const int4*)(dst + base);
    for (int i = threadIdx.x; i < cnt4; i += TPB) {
        int4 s = s4[i];
        int4 d = d4[i];
        int b, p;
        b = d.x >> BUCKET_BITS; p = atomicAdd(&offs[b], 1);
        packed[p] = ((unsigned)(d.x & (BUCKET_SZ - 1)) << SRC_BITS) | (unsigned)s.x;
        b = d.y >> BUCKET_BITS; p = atomicAdd(&offs[b], 1);
        packed[p] = ((unsigned)(d.y & (BUCKET_SZ - 1)) << SRC_BITS) | (unsigned)s.y;
        b = d.z >> BUCKET_BITS; p = atomicAdd(&offs[b], 1);
        packed[p] = ((unsigned)(d.z & (BUCKET_SZ - 1)) << SRC_BITS) | (unsigned)s.z;
        b = d.w >> BUCKET_BITS; p = atomicAdd(&offs[b], 1);
        packed[p] = ((unsigned)(d.w & (BUCKET_SZ - 1)) << SRC_BITS) | (unsigned)s.w;
    }
    for (int e = base + (cnt4 << 2) + threadIdx.x; e < end; e += TPB) {
        int s = src[e], d = dst[e];
        int b = d >> BUCKET_BITS;
        int p = atomicAdd(&offs[b], 1);
        packed[p] = ((unsigned)(d & (BUCKET_SZ - 1)) << SRC_BITS) | (unsigned)s;
    }
}

// ---- per-bucket CSR: count + scan -> row/deg/dinv, fill perm (src only) ----
__global__ __launch_bounds__(TPB_CSR) void k_csr(const unsigned* __restrict__ packed,
                                                 const int* __restrict__ scanned,
                                                 int E, int n, int NB, int nChunks,
                                                 int* __restrict__ row,
                                                 int* __restrict__ deg,
                                                 float* __restrict__ dinv,
                                                 int* __restrict__ perm) {
    __shared__ int cnt[BUCKET_SZ];
    __shared__ int off_[BUCKET_SZ];
    __shared__ int waveTot[TPB_CSR / 64];
    int bk = blockIdx.x, tid = threadIdx.x;
    int base = bk << BUCKET_BITS;
    int nNodes = min(BUCKET_SZ, n - base);
    int s0 = scanned[(size_t)bk * nChunks];
    int s1 = (bk + 1 < NB) ? scanned[(size_t)(bk + 1) * nChunks] : E;

    cnt[tid] = 0; cnt[tid + TPB_CSR] = 0;
    __syncthreads();
    // count (uint4-unrolled stream of packed)
    {
        int a0 = (s0 + 3) & ~3; if (a0 > s1) a0 = s1;
        int a1 = s1 & ~3;
        if (tid < a0 - s0) atomicAdd(&cnt[packed[s0 + tid] >> SRC_BITS], 1);
        const uint4* p4 = (const uint4*)packed;
        for (int i = (a0 >> 2) + tid; i < (a1 >> 2); i += TPB_CSR) {
            uint4 u = p4[i];
            atomicAdd(&cnt[u.x >> SRC_BITS], 1);
            atomicAdd(&cnt[u.y >> SRC_BITS], 1);
            atomicAdd(&cnt[u.z >> SRC_BITS], 1);
            atomicAdd(&cnt[u.w >> SRC_BITS], 1);
        }
        if (a1 >= a0 && tid < s1 - a1) atomicAdd(&cnt[packed[a1 + tid] >> SRC_BITS], 1);
    }
    __syncthreads();

    // exclusive scan of cnt[0..1023], 2 elems/thread
    int v0 = cnt[2 * tid], v1 = cnt[2 * tid + 1];
    int s = v0 + v1;
    int lane = tid & 63, wave = tid >> 6;
    int t = s;
#pragma unroll
    for (int o = 1; o < 64; o <<= 1) {
        int u = __shfl_up(t, o, 64);
        if (lane >= o) t += u;
    }
    if (lane == 63) waveTot[wave] = t;
    __syncthreads();
    int wOff = 0;
    for (int w = 0; w < wave; w++) wOff += waveTot[w];
    int ex = wOff + (t - s);
    off_[2 * tid] = ex;
    off_[2 * tid + 1] = ex + v0;
    __syncthreads();

    for (int j = tid; j < nNodes; j += TPB_CSR) {
        int c = cnt[j];
        deg[base + j] = c;
        row[base + j] = s0 + off_[j];
        dinv[base + j] = rsqrtf((float)(c + 1));
    }
    __syncthreads();

    // fill perm (src index only)
    {
        int a0 = (s0 + 3) & ~3; if (a0 > s1) a0 = s1;
        int a1 = s1 & ~3;
        if (tid < a0 - s0) {
            unsigned u = packed[s0 + tid];
            int p = atomicAdd(&off_[u >> SRC_BITS], 1);
            perm[s0 + p] = (int)(u & SRC_MASK);
        }
        const uint4* p4 = (const uint4*)packed;
        for (int i = (a0 >> 2) + tid; i < (a1 >> 2); i += TPB_CSR) {
            uint4 u = p4[i];
            int p;
            p = atomicAdd(&off_[u.x >> SRC_BITS], 1); perm[s0 + p] = (int)(u.x & SRC_MASK);
            p = atomicAdd(&off_[u.y >> SRC_BITS], 1); perm[s0 + p] = (int)(u.y & SRC_MASK);
            p = atomicAdd(&off_[u.z >> SRC_BITS], 1); perm[s0 + p] = (int)(u.z & SRC_MASK);
            p = atomicAdd(&off_[u.w >> SRC_BITS], 1); perm[s0 + p] = (int)(u.w & SRC_MASK);
        }
        if (a1 >= a0 && tid < s1 - a1) {
            unsigned u = packed[a1 + tid];
            int p = atomicAdd(&off_[u >> SRC_BITS], 1);
            perm[s0 + p] = (int)(u & SRC_MASK);
        }
    }
}

// ============================ atomic-free gather layers (fp16 hs) ============================
// 16 lanes per node; register accumulation; shfl_xor reduce; fused dense epilogue.

__global__ __launch_bounds__(TPB) void k_gather_l1(const int* __restrict__ row,
                                                   const int* __restrict__ deg,
                                                   const int* __restrict__ perm,
                                                   const __half* __restrict__ hs_in,
                                                   const float* __restrict__ dinv,
                                                   const float* __restrict__ W,
                                                   const float* __restrict__ b,
                                                   __half* __restrict__ hs_out, int n) {
    int node = blockIdx.x * (TPB / 16) + (threadIdx.x >> 4);
    int lane = threadIdx.x & 15;
    if (node >= n) return;
    int start = row[node];
    int d = deg[node];
    float4 s = make_float4(0.f, 0.f, 0.f, 0.f);
    int j = lane;
    for (; j + 16 < d; j += 32) {
        int u0 = __builtin_nontemporal_load(perm + start + j);
        int u1 = __builtin_nontemporal_load(perm + start + j + 16);
        float4 a = ld_h4(hs_in, u0);
        float4 c = ld_h4(hs_in, u1);
        s.x += a.x + c.x; s.y += a.y + c.y; s.z += a.z + c.z; s.w += a.w + c.w;
    }
    if (j < d) {
        int u = __builtin_nontemporal_load(perm + start + j);
        float4 a = ld_h4(hs_in, u);
        s.x += a.x; s.y += a.y; s.z += a.z; s.w += a.w;
    }
#pragma unroll
    for (int off = 8; off >= 1; off >>= 1) {
        s.x += __shfl_xor(s.x, off, 16);
        s.y += __shfl_xor(s.y, off, 16);
        s.z += __shfl_xor(s.z, off, 16);
        s.w += __shfl_xor(s.w, off, 16);
    }
    if (lane == 0) {
        float4 self = ld_h4(hs_in, node);
        s.x += self.x; s.y += self.y; s.z += self.z; s.w += self.w;
        float dv = dinv[node];
        float h0 = fmaxf(fmaf(dv, s.x, b[0]), 0.f);
        float h1 = fmaxf(fmaf(dv, s.y, b[1]), 0.f);
        float h2 = fmaxf(fmaf(dv, s.z, b[2]), 0.f);
        float h3 = fmaxf(fmaf(dv, s.w, b[3]), 0.f);
        float4 r;
        r.x = dv * (h0 * W[0] + h1 * W[4] + h2 * W[8]  + h3 * W[12]);
        r.y = dv * (h0 * W[1] + h1 * W[5] + h2 * W[9]  + h3 * W[13]);
        r.z = dv * (h0 * W[2] + h1 * W[6] + h2 * W[10] + h3 * W[14]);
        r.w = dv * (h0 * W[3] + h1 * W[7] + h2 * W[11] + h3 * W[15]);
        st_h4(hs_out, node, r);
    }
}

__global__ __launch_bounds__(TPB) void k_gather_l2(const int* __restrict__ row,
                                                   const int* __restrict__ deg,
                                                   const int* __restrict__ perm,
                                                   const __half* __restrict__ hs_in,
                                                   const float* __restrict__ dinv,
                                                   const float* __restrict__ W,
                                                   const float* __restrict__ b,
                                                   __half* __restrict__ hs_out, int n) {
    int node = blockIdx.x * (TPB / 16) + (threadIdx.x >> 4);
    int lane = threadIdx.x & 15;
    if (node >= n) return;
    int start = row[node];
    int d = deg[node];
    float4 s = make_float4(0.f, 0.f, 0.f, 0.f);
    int j = lane;
    for (; j + 16 < d; j += 32) {
        int u0 = __builtin_nontemporal_load(perm + start + j);
        int u1 = __builtin_nontemporal_load(perm + start + j + 16);
        float4 a = ld_h4(hs_in, u0);
        float4 c = ld_h4(hs_in, u1);
        s.x += a.x + c.x; s.y += a.y + c.y; s.z += a.z + c.z; s.w += a.w + c.w;
    }
    if (j < d) {
        int u = __builtin_nontemporal_load(perm + start + j);
        float4 a = ld_h4(hs_in, u);
        s.x += a.x; s.y += a.y; s.z += a.z; s.w += a.w;
    }
#pragma unroll
    for (int off = 8; off >= 1; off >>= 1) {
        s.x += __shfl_xor(s.x, off, 16);
        s.y += __shfl_xor(s.y, off, 16);
        s.z += __shfl_xor(s.z, off, 16);
        s.w += __shfl_xor(s.w, off, 16);
    }
    if (lane == 0) {
        float4 self = ld_h4(hs_in, node);
        s.x += self.x; s.y += self.y; s.z += self.z; s.w += self.w;
        float dv = dinv[node];
        float h0 = fmaxf(fmaf(dv, s.x, b[0]), 0.f);
        float h1 = fmaxf(fmaf(dv, s.y, b[1]), 0.f);
        float h2 = fmaxf(fmaf(dv, s.z, b[2]), 0.f);
        float h3 = fmaxf(fmaf(dv, s.w, b[3]), 0.f);
        float2 r;
        r.x = dv * (h0 * W[0] + h1 * W[2] + h2 * W[4] + h3 * W[6]);
        r.y = dv * (h0 * W[1] + h1 * W[3] + h2 * W[5] + h3 * W[7]);
        st_h2(hs_out, node, r);
    }
}

__global__ __launch_bounds__(TPB) void k_gather_l3(const int* __restrict__ row,
                                                   const int* __restrict__ deg,
                                                   const int* __restrict__ perm,
                                                   const __half* __restrict__ hs_in,
                                                   const float* __restrict__ dinv,
                                                   const float* __restrict__ b,
                                                   float* __restrict__ out, int n) {
    int node = blockIdx.x * (TPB / 16) + (threadIdx.x >> 4);
    int lane = threadIdx.x & 15;
    if (node >= n) return;
    int start = row[node];
    int d = deg[node];
    float2 s = make_float2(0.f, 0.f);
    int j = lane;
    for (; j + 16 < d; j += 32) {
        int u0 = __builtin_nontemporal_load(perm + start + j);
        int u1 = __builtin_nontemporal_load(perm + start + j + 16);
        float2 a = ld_h2(hs_in, u0);
        float2 c = ld_h2(hs_in, u1);
        s.x += a.x + c.x; s.y += a.y + c.y;
    }
    if (j < d) {
        int u = __builtin_nontemporal_load(perm + start + j);
        float2 a = ld_h2(hs_in, u);
        s.x += a.x; s.y += a.y;
    }
#pragma unroll
    for (int off = 8; off >= 1; off >>= 1) {
        s.x += __shfl_xor(s.x, off, 16);
        s.y += __shfl_xor(s.y, off, 16);
    }
    if (lane == 0) {
        float2 self = ld_h2(hs_in, node);
        s.x += self.x; s.y += self.y;
        float dv = dinv[node];
        float2 o;
        o.x = fmaf(dv, s.x, b[0]);
        o.y = fmaf(dv, s.y, b[1]);
        *(float2*)(out + (size_t)node * 2) = o;
    }
}

// ==================== fallback (round-1 global-atomic path, fp32, verified) ====================

__global__ __launch_bounds__(TPB) void k_degree(const int* __restrict__ dst,
                                                int* __restrict__ deg, int E) {
    int e4 = E >> 2;
    int i = blockIdx.x * TPB + threadIdx.x;
    if (i < e4) {
        int4 d = ((const int4*)dst)[i];
        atomicAdd(&deg[d.x], 1);
        atomicAdd(&deg[d.y], 1);
        atomicAdd(&deg[d.z], 1);
        atomicAdd(&deg[d.w], 1);
    }
    if (i < (E & 3)) atomicAdd(&deg[dst[(e4 << 2) + i]], 1);
}

__global__ __launch_bounds__(TPB) void k_dinv(const int* __restrict__ deg,
                                              float* __restrict__ dinv, int n) {
    int i = blockIdx.x * TPB + threadIdx.x;
    if (i >= n) return;
    dinv[i] = rsqrtf((float)(deg[i] + 1));
}

__global__ __launch_bounds__(TPB) void k_xform1_acc(const float* __restrict__ x,
                                                    const float* __restrict__ W,
                                                    const float* __restrict__ dinv,
                                                    float* __restrict__ hs,
                                                    float* __restrict__ acc, int n) {
    int node = blockIdx.x * (TPB / 32) + (threadIdx.x >> 5);
    int lane = threadIdx.x & 31;
    if (node >= n) return;
    int k = lane * 4;
    float4 xv = *(const float4*)(x + (size_t)node * 128 + k);
    float4 w0 = *(const float4*)(W + (size_t)(k + 0) * 4);
    float4 w1 = *(const float4*)(W + (size_t)(k + 1) * 4);
    float4 w2 = *(const float4*)(W + (size_t)(k + 2) * 4);
    float4 w3 = *(const float4*)(W + (size_t)(k + 3) * 4);
    float p0 = xv.x * w0.x + xv.y * w1.x + xv.z * w2.x + xv.w * w3.x;
    float p1 = xv.x * w0.y + xv.y * w1.y + xv.z * w2.y + xv.w * w3.y;
    float p2 = xv.x * w0.z + xv.y * w1.z + xv.z * w2.z + xv.w * w3.z;
    float p3 = xv.x * w0.w + xv.y * w1.w + xv.z * w2.w + xv.w * w3.w;
#pragma unroll
    for (int off = 16; off >= 1; off >>= 1) {
        p0 += __shfl_down(p0, off, 32);
        p1 += __shfl_down(p1, off, 32);
        p2 += __shfl_down(p2, off, 32);
        p3 += __shfl_down(p3, off, 32);
    }
    if (lane == 0) {
        float dv = dinv[node];
        float4 r = make_float4(dv * p0, dv * p1, dv * p2, dv * p3);
        *(float4*)(hs + (size_t)node * 4)  = r;
        *(float4*)(acc + (size_t)node * 4) = r;
    }
}

__global__ __launch_bounds__(TPB) void k_scatter4(const int* __restrict__ src,
                                                  const int* __restrict__ dst,
                                                  const float* __restrict__ hs,
                                                  float* __restrict__ acc, int E) {
    int e4 = E >> 2;
    int i = blockIdx.x * TPB + threadIdx.x;
    if (i < e4) {
        int4 s = ((const int4*)src)[i];
        int4 d = ((const int4*)dst)[i];
        float4 v0 = *(const float4*)(hs + (size_t)s.x * 4);
        float4 v1 = *(const float4*)(hs + (size_t)s.y * 4);
        float4 v2 = *(const float4*)(hs + (size_t)s.z * 4);
        float4 v3 = *(const float4*)(hs + (size_t)s.w * 4);
        float* a;
        a = acc + (size_t)d.x * 4;
        atomAddF(a + 0, v0.x); atomAddF(a + 1, v0.y); atomAddF(a + 2, v0.z); atomAddF(a + 3, v0.w);
        a = acc + (size_t)d.y * 4;
        atomAddF(a + 0, v1.x); atomAddF(a + 1, v1.y); atomAddF(a + 2, v1.z); atomAddF(a + 3, v1.w);
        a = acc + (size_t)d.z * 4;
        atomAddF(a + 0, v2.x); atomAddF(a + 1, v2.y); atomAddF(a + 2, v2.z); atomAddF(a + 3, v2.w);
        a = acc + (size_t)d.w * 4;
        atomAddF(a + 0, v3.x); atomAddF(a + 1, v3.y); atomAddF(a + 2, v3.z); atomAddF(a + 3, v3.w);
    }
    if (i < (E & 3)) {
        int e = (e4 << 2) + i;
        int s = src[e], d = dst[e];
        float4 v = *(const float4*)(hs + (size_t)s * 4);
        float* a = acc + (size_t)d * 4;
        atomAddF(a + 0, v.x); atomAddF(a + 1, v.y); atomAddF(a + 2, v.z); atomAddF(a + 3, v.w);
    }
}

__global__ __launch_bounds__(TPB) void k_scatter2(const int* __restrict__ src,
                                                  const int* __restrict__ dst,
                                                  const float* __restrict__ hs,
                                                  float* __restrict__ acc, int E) {
    int e4 = E >> 2;
    int i = blockIdx.x * TPB + threadIdx.x;
    if (i < e4) {
        int4 s = ((const int4*)src)[i];
        int4 d = ((const int4*)dst)[i];
        float2 v0 = *(const float2*)(hs + (size_t)s.x * 2);
        float2 v1 = *(const float2*)(hs + (size_t)s.y * 2);
        float2 v2 = *(const float2*)(hs + (size_t)s.z * 2);
        float2 v3 = *(const float2*)(hs + (size_t)s.w * 2);
        float* a;
        a = acc + (size_t)d.x * 2; atomAddF(a + 0, v0.x); atomAddF(a + 1, v0.y);
        a = acc + (size_t)d.y * 2; atomAddF(a + 0, v1.x); atomAddF(a + 1, v1.y);
        a = acc + (size_t)d.z * 2; atomAddF(a + 0, v2.x); atomAddF(a + 1, v2.y);
        a = acc + (size_t)d.w * 2; atomAddF(a + 0, v3.x); atomAddF(a + 1, v3.y);
    }
    if (i < (E & 3)) {
        int e = (e4 << 2) + i;
        int s = src[e], d = dst[e];
        float2 v = *(const float2*)(hs + (size_t)s * 2);
        float* a = acc + (size_t)d * 2;
        atomAddF(a + 0, v.x); atomAddF(a + 1, v.y);
    }
}

__global__ __launch_bounds__(TPB) void k_xform2(const float* __restrict__ acc_in,
                                                const float* __restrict__ dinv,
                                                const float* __restrict__ W,
                                                const float* __restrict__ b,
                                                float* __restrict__ hs,
                                                float* __restrict__ acc, int n) {
    int i = blockIdx.x * TPB + threadIdx.x;
    if (i >= n) return;
    float dv = dinv[i];
    float4 a = *(const float4*)(acc_in + (size_t)i * 4);
    float h0 = fmaxf(fmaf(dv, a.x, b[0]), 0.f);
    float h1 = fmaxf(fmaf(dv, a.y, b[1]), 0.f);
    float h2 = fmaxf(fmaf(dv, a.z, b[2]), 0.f);
    float h3 = fmaxf(fmaf(dv, a.w, b[3]), 0.f);
    float4 r;
    r.x = dv * (h0 * W[0] + h1 * W[4] + h2 * W[8]  + h3 * W[12]);
    r.y = dv * (h0 * W[1] + h1 * W[5] + h2 * W[9]  + h3 * W[13]);
    r.z = dv * (h0 * W[2] + h1 * W[6] + h2 * W[10] + h3 * W[14]);
    r.w = dv * (h0 * W[3] + h1 * W[7] + h2 * W[11] + h3 * W[15]);
    *(float4*)(hs + (size_t)i * 4)  = r;
    *(float4*)(acc + (size_t)i * 4) = r;
}

__global__ __launch_bounds__(TPB) void k_xform3(const float* __restrict__ acc_in,
                                                const float* __restrict__ dinv,
                                                const float* __restrict__ W,
                                                const float* __restrict__ b,
                                                float* __restrict__ hs,
                                                float* __restrict__ acc, int n) {
    int i = blockIdx.x * TPB + threadIdx.x;
    if (i >= n) return;
    float dv = dinv[i];
    float4 a = *(const float4*)(acc_in + (size_t)i * 4);
    float h0 = fmaxf(fmaf(dv, a.x, b[0]), 0.f);
    float h1 = fmaxf(fmaf(dv, a.y, b[1]), 0.f);
    float h2 = fmaxf(fmaf(dv, a.z, b[2]), 0.f);
    float h3 = fmaxf(fmaf(dv, a.w, b[3]), 0.f);
    float2 r;
    r.x = dv * (h0 * W[0] + h1 * W[2] + h2 * W[4] + h3 * W[6]);
    r.y = dv * (h0 * W[1] + h1 * W[3] + h2 * W[5] + h3 * W[7]);
    *(float2*)(hs + (size_t)i * 2)  = r;
    *(float2*)(acc + (size_t)i * 2) = r;
}

__global__ __launch_bounds__(TPB) void k_final(const float* __restrict__ acc_in,
                                               const float* __restrict__ dinv,
                                               const float* __restrict__ b,
                                               float* __restrict__ out, int n) {
    int i = blockIdx.x * TPB + threadIdx.x;
    if (i >= n) return;
    float dv = dinv[i];
    float2 a = *(const float2*)(acc_in + (size_t)i * 2);
    float2 o;
    o.x = fmaf(dv, a.x, b[0]);
    o.y = fmaf(dv, a.y, b[1]);
    *(float2*)(out + (size_t)i * 2) = o;
}

// ============================ launch ============================

extern "C" void kernel_launch(void* const* d_in, const int* in_sizes, int n_in,
                              void* d_out, int out_size, void* d_ws, size_t ws_size,
                              hipStream_t stream) {
    const float* x  = (const float*)d_in[0];
    const int*   ei = (const int*)d_in[1];
    const float* W1 = (const float*)d_in[2];
    const float* b1 = (const float*)d_in[3];
    const float* W2 = (const float*)d_in[4];
    const float* b2 = (const float*)d_in[5];
    const float* W3 = (const float*)d_in[6];
    const float* b3 = (const float*)d_in[7];
    float* out = (float*)d_out;

    const int n = in_sizes[0] / 128;   // 500000
    const int E = in_sizes[1] / 2;     // 16000000
    const int* src = ei;
    const int* dst = ei + E;
    (void)n_in; (void)out_size;

    char* ws = (char*)d_ws;
    size_t off = 0;
    auto alloc = [&](size_t bytes) -> char* {
        char* p = ws + off;
        off += (bytes + 255) & ~(size_t)255;
        return p;
    };

    const int NB = (n + BUCKET_SZ - 1) >> BUCKET_BITS;            // 489
    const int nChunks = (E + CHUNK - 1) / CHUNK;                  // 489
    const size_t histN = (size_t)NB * nChunks;
    const int nScanBlocksH = (int)((histN + SCAN_CHUNK - 1) / SCAN_CHUNK);

    int gridN  = (n + TPB - 1) / TPB;
    int gridX1 = (n + (TPB / 32) - 1) / (TPB / 32);
    int gridG  = (n + (TPB / 16) - 1) / (TPB / 16);

    // packed-path workspace requirement
    size_t need = 0;
    {
        size_t t = 0;
        auto acct = [&](size_t bytes) { t += (bytes + 255) & ~(size_t)255; };
        acct((size_t)n * 4);            // dinv
        acct((size_t)n * 4);            // row
        acct((size_t)n * 4);            // deg
        acct((size_t)n * 8);            // hs1 (fp16 x4)
        acct((size_t)n * 8);            // hs2 (fp16 x4)
        acct((size_t)n * 4);            // hs3 (fp16 x2)
        acct((size_t)E * 4);            // packed
        acct((size_t)E * 4);            // perm
        acct(histN * 4);                // hist
        acct((size_t)nScanBlocksH * 4); // bsums
        acct(256);                      // dummy
        need = t;
    }

    bool packedOK = (n <= (1 << SRC_BITS)) && (NB <= NB_MAX) &&
                    (nScanBlocksH <= SCAN_CHUNK) && (ws_size >= need);

    if (packedOK) {
        float*    dinv   = (float*)alloc((size_t)n * 4);
        int*      row    = (int*)  alloc((size_t)n * 4);
        int*      deg    = (int*)  alloc((size_t)n * 4);
        __half*   hs1    = (__half*)alloc((size_t)n * 8);
        __half*   hs2    = (__half*)alloc((size_t)n * 8);
        __half*   hs3    = (__half*)alloc((size_t)n * 4);
        unsigned* packed = (unsigned*)alloc((size_t)E * 4);
        int*      perm   = (int*)  alloc((size_t)E * 4);
        int*      hist   = (int*)  alloc(histN * 4);
        int*      bsums  = (int*)  alloc((size_t)nScanBlocksH * 4);
        int*      dummy  = (int*)  alloc(256);

        // bucket-sort edges by dst, then CSR within buckets (no global atomics)
        k_hist<<<nChunks, TPB, 0, stream>>>(dst, E, hist, NB, nChunks);
        k_scan_block<<<nScanBlocksH, TPB, 0, stream>>>(hist, hist, bsums, (int)histN);
        k_scan_block<<<1, TPB, 0, stream>>>(bsums, bsums, dummy, nScanBlocksH);
        k_scan_add<<<(int)((histN + TPB - 1) / TPB), TPB, 0, stream>>>(hist, bsums, (int)histN);
        k_part<<<nChunks, TPB, 0, stream>>>(src, dst, E, hist, packed, NB, nChunks);
        k_csr<<<NB, TPB_CSR, 0, stream>>>(packed, hist, E, n, NB, nChunks, row, deg, dinv, perm);

        // layers: atomic-free register-accumulating gathers, fp16 inter-layer storage
        k_xform1<<<gridX1, TPB, 0, stream>>>(x, W1, dinv, hs1, n);
        k_gather_l1<<<gridG, TPB, 0, stream>>>(row, deg, perm, hs1, dinv, W2, b1, hs2, n);
        k_gather_l2<<<gridG, TPB, 0, stream>>>(row, deg, perm, hs2, dinv, W3, b2, hs3, n);
        k_gather_l3<<<gridG, TPB, 0, stream>>>(row, deg, perm, hs3, dinv, b3, out, n);
    } else {
        // fallback: round-1 global-atomic scatter path (fp32, verified)
        int e4 = E >> 2;
        int gridE = (e4 > 0 ? (e4 + TPB - 1) / TPB : 1);

        int*   deg  = (int*)  alloc((size_t)n * 4);
        float* dinv = (float*)alloc((size_t)n * 4);
        float* hs1  = (float*)alloc((size_t)n * 16);
        float* acc1 = (float*)alloc((size_t)n * 16);
        float* hs2  = (float*)alloc((size_t)n * 16);
        float* acc2 = (float*)alloc((size_t)n * 16);
        float* hs3  = (float*)alloc((size_t)n * 8);
        float* acc3 = (float*)alloc((size_t)n * 8);

        hipMemsetAsync(deg, 0, (size_t)n * 4, stream);

        k_degree<<<gridE, TPB, 0, stream>>>(dst, deg, E);
        k_dinv<<<gridN, TPB, 0, stream>>>(deg, dinv, n);

        k_xform1_acc<<<gridX1, TPB, 0, stream>>>(x, W1, dinv, hs1, acc1, n);
        k_scatter4<<<gridE, TPB, 0, stream>>>(src, dst, hs1, acc1, E);
        k_xform2<<<gridN, TPB, 0, stream>>>(acc1, dinv, W2, b1, hs2, acc2, n);
        k_scatter4<<<gridE, TPB, 0, stream>>>(src, dst, hs2, acc2, E);
        k_xform3<<<gridN, TPB, 0, stream>>>(acc2, dinv, W3, b2, hs3, acc3, n);
        k_scatter2<<<gridE, TPB, 0, stream>>>(src, dst, hs3, acc3, E);
        k_final<<<gridN, TPB, 0, stream>>>(acc3, dinv, b3, out, n);
    }
}